// Round 13
// baseline (7157.059 us; speedup 1.0000x reference)
//
#include <hip/hip_runtime.h>

typedef short s16x8 __attribute__((ext_vector_type(8)));
typedef short s16x4 __attribute__((ext_vector_type(4)));
typedef float f32x4 __attribute__((ext_vector_type(4)));
typedef unsigned long long u64;

#define T_N 2048
#define B_N 64
#define H_N 256
#define I_N 256
#define HY_BYTES ((size_t)134217728)   // 4 * T * B * H
// v3: exch u64[2 slot][8 wg][8 wv][16 row][8 colpair] = 128 KB, A-layout+ctr
#define WS_V3 131072
// v1 (r10): exch 64KB + u32 flags[64]
#define EXCH_BYTES 65536
#define WS_V1 (EXCH_BYTES + 256)

static __device__ __forceinline__ short f2bf(float f) {
    unsigned u = __builtin_bit_cast(unsigned, f);
    u += 0x7FFFu + ((u >> 16) & 1u);   // RNE
    return (short)(u >> 16);
}
static __device__ __forceinline__ float bf2f(short h) {
    unsigned u = ((unsigned)(unsigned short)h) << 16;
    return __builtin_bit_cast(float, u);
}
static __device__ __forceinline__ float e2c(float a) {
    return __builtin_amdgcn_exp2f(fminf(a, 126.0f));
}
static __device__ __forceinline__ s16x4 ntl4(const void* p) {
    return __builtin_nontemporal_load((const s16x4*)p);
}
static __device__ __forceinline__ u64 ald(const u64* p) {
    return __hip_atomic_load(p, __ATOMIC_RELAXED, __HIP_MEMORY_SCOPE_AGENT);
}
static __device__ __forceinline__ void ast(u64* p, u64 v) {
    __hip_atomic_store(p, v, __ATOMIC_RELAXED, __HIP_MEMORY_SCOPE_AGENT);
}

#define C1 1.44269504088896340f   // log2(e)
#define C2 2.88539008177792681f   // 2*log2(e)

#define MFMA(a, b, c) __builtin_amdgcn_mfma_f32_16x16x32_bf16(a, b, c, 0, 0, 0)

// exch u64 index: [slot][wg][wv][row][colpair], colpair 0..7 WITHIN the wave
#define PV_IDX(S, WG, WV, ROW, CP) \
    ((((((size_t)(S)) * 8 + (WG)) * 8 + (WV)) * 16 + (ROW)) * 8 + (CP))

// ---------------------------------------------------------------------------
// zero flags (v1 fallback path only)
// ---------------------------------------------------------------------------
__global__ void zero_flags(char* __restrict__ ws) {
    if (threadIdx.x < 64) ((unsigned*)(ws + EXCH_BYTES))[threadIdx.x] = 0u;
}

// ---------------------------------------------------------------------------
// Phase 1: xg = x @ w_ih^T + bias, pre-scaled by -C1 (i,f,o) / -C2 (g),
// bf16 in MFMA C-fragment layout inside d_out (unchanged).
// ---------------------------------------------------------------------------
__global__ __launch_bounds__(512) void xg_gemm(
        const float* __restrict__ x, const float* __restrict__ w_ih,
        const float* __restrict__ b_ih, const float* __restrict__ b_hh,
        char* __restrict__ out)
{
    const int tid  = threadIdx.x;
    const int wave = tid >> 6;
    const int lane = tid & 63;
    const int l15  = lane & 15;
    const int kg   = lane >> 4;

    __shared__ short Blds[8192];

    const int m16 = blockIdx.x * 8 + wave;
    const int by  = blockIdx.y;
    const int n0  = by * 256;

    const float* xrow = x + (size_t)(m16 * 16 + l15) * I_N;

    f32x4 acc[16] = {};

#pragma unroll 1
    for (int ks = 0; ks < 8; ++ks) {
        __syncthreads();
#pragma unroll
        for (int h = 0; h < 2; ++h) {
            int nl = (tid >> 2) + h * 128;
            int c  = tid & 3;
            const float* wp = w_ih + (size_t)(n0 + nl) * I_N + ks * 32 + c * 8;
            f32x4 w0 = *(const f32x4*)(wp);
            f32x4 w1 = *(const f32x4*)(wp + 4);
            s16x8 bv;
            bv[0]=f2bf(w0[0]); bv[1]=f2bf(w0[1]); bv[2]=f2bf(w0[2]); bv[3]=f2bf(w0[3]);
            bv[4]=f2bf(w1[0]); bv[5]=f2bf(w1[1]); bv[6]=f2bf(w1[2]); bv[7]=f2bf(w1[3]);
            int dt = nl >> 4;
            int lp = (nl & 15) + 16 * c;
            *(s16x8*)(&Blds[(dt * 64 + lp) * 8]) = bv;
        }
        __syncthreads();
        const float* ap = xrow + ks * 32 + kg * 8;
        f32x4 a0 = *(const f32x4*)(ap);
        f32x4 a1 = *(const f32x4*)(ap + 4);
        s16x8 av;
        av[0]=f2bf(a0[0]); av[1]=f2bf(a0[1]); av[2]=f2bf(a0[2]); av[3]=f2bf(a0[3]);
        av[4]=f2bf(a1[0]); av[5]=f2bf(a1[1]); av[6]=f2bf(a1[2]); av[7]=f2bf(a1[3]);
#pragma unroll
        for (int dt = 0; dt < 16; ++dt) {
            s16x8 bv = *(const s16x8*)(&Blds[(dt * 64 + lane) * 8]);
            acc[dt] = MFMA(av, bv, acc[dt]);
        }
    }

    const int t = m16 >> 2;
    const int g = m16 & 3;
#pragma unroll
    for (int dt = 0; dt < 16; ++dt) {
        int tau = by * 16 + dt;
        int n   = tau * 16 + l15;
        float bias = b_ih[n] + b_hh[n];
        float scale = ((tau >> 4) == 2) ? -C2 : -C1;
        size_t base = (tau < 32)
            ? ((size_t)t * 65536 + (size_t)g * 16384 + (size_t)tau * 512)
            : (HY_BYTES + (size_t)t * 65536 + (size_t)g * 16384 + (size_t)(tau - 32) * 512);
        s16x4 o;
        o[0] = f2bf(scale * (acc[dt][0] + bias));
        o[1] = f2bf(scale * (acc[dt][1] + bias));
        o[2] = f2bf(scale * (acc[dt][2] + bias));
        o[3] = f2bf(scale * (acc[dt][3] + bias));
        *(s16x4*)(out + base + lane * 8) = o;
    }
}

// ---------------------------------------------------------------------------
// Phase 2 v3 (FIXED publish indexing): speculative A-layout exchange.
// h published in A-fragment arrangement with a step counter embedded in
// every u64 word.  Reader issues all 16 pv loads at step TOP, runs own-half
// k-slices, validates embedded ctrs (loads landed under own MFMA), feeds
// assembled frags straight into partner-half MFMAs.  No partner LDS staging,
// no separate poll target, no writer drain.  W tiles f,g live in LDS to fund
// the pv registers.  Sticky bounded retry: broken sync -> fast absmax fail.
// r12 bug: publisher used cp = w*8+(l15>>1) while also passing WV=w
// (wave offset double-counted -> aliasing).  Fix: cp = l15>>1.
// ---------------------------------------------------------------------------
__global__ __launch_bounds__(512)
__attribute__((amdgpu_waves_per_eu(2, 2)))
void lstm_rec8v3(
        const float* __restrict__ h0, const float* __restrict__ c0,
        const float* __restrict__ w_hh, char* __restrict__ out,
        char* __restrict__ ws)
{
    const int b    = blockIdx.x;       // 0..7
    const int g    = b & 3;
    const int hf   = b >> 2;
    const int tid  = threadIdx.x;
    const int w    = tid >> 6;
    const int lane = tid & 63;
    const int l15  = lane & 15;
    const int kg   = lane >> 4;

    const int tc   = hf * 8 + w;       // my col-tile (0..15)
    const int col  = tc * 16 + l15;    // my global h-col
    const int lc   = w * 16 + l15;     // my col within own half
    const int oks  = 4 * hf;           // own k-slice base (global)
    const int pks  = 4 * (hf ^ 1);     // partner k-slice base

    __shared__ short hlds[2][2048];    // [2][16 rows][128 cols] bf16, swizzled
    __shared__ short wlds[65536];      // W tiles q=1 (f), q=2 (g): 128 KB

    u64* exch = (u64*)ws;

    // ---- W fragments: q=0 (i), q=3 (o) in regs; q=1,2 in LDS ----
    s16x8 wreg0[8], wreg3[8];
#pragma unroll
    for (int q = 0; q < 4; ++q) {
        const int tau = 16 * q + tc;
        const float scale = (q == 2) ? -C2 : -C1;
        const float* wp = w_hh + (size_t)(tau * 16 + l15) * H_N;
#pragma unroll
        for (int ks = 0; ks < 8; ++ks) {
            const float* p = wp + ks * 32 + kg * 8;
            f32x4 w0 = *(const f32x4*)(p);
            f32x4 w1 = *(const f32x4*)(p + 4);
            s16x8 v;
            v[0]=f2bf(scale*w0[0]); v[1]=f2bf(scale*w0[1]);
            v[2]=f2bf(scale*w0[2]); v[3]=f2bf(scale*w0[3]);
            v[4]=f2bf(scale*w1[0]); v[5]=f2bf(scale*w1[1]);
            v[6]=f2bf(scale*w1[2]); v[7]=f2bf(scale*w1[3]);
            if (q == 0)      wreg0[ks] = v;
            else if (q == 3) wreg3[ks] = v;
            else *(s16x8*)(&wlds[(((q - 1) * 8 + w) * 8 + ks) * 512 + lane * 8]) = v;
        }
    }

    // ---- h0 own half -> hlds[0] ----
    {
        const int row  = tid >> 5;             // 16 rows x 32 threads
        const int col0 = (tid & 31) * 4;
        const int sw = (row & 7) << 4;
        const float* hp = h0 + (size_t)(g * 16 + row) * H_N + hf * 128 + col0;
#pragma unroll
        for (int j = 0; j < 4; ++j) {
            int byte = row * 256 + ((2 * (col0 + j)) ^ sw);
            *(short*)((char*)hlds[0] + byte) = f2bf(hp[j]);
        }
    }

    // ---- publish own-half h0 (slot 0, ctr 0) in A-layout ----
    {
        unsigned pk[4];
#pragma unroll
        for (int r = 0; r < 4; ++r)
            pk[r] = (unsigned)(unsigned short)f2bf(
                h0[(size_t)(g * 16 + kg * 4 + r) * H_N + col]);
        unsigned nb[4];
#pragma unroll
        for (int r = 0; r < 4; ++r) nb[r] = __shfl_xor(pk[r], 1, 64);
        if (!(l15 & 1)) {
            int cp = l15 >> 1;                 // FIX: within-wave colpair 0..7
#pragma unroll
            for (int r = 0; r < 4; ++r)
                ast(exch + PV_IDX(0, b, w, kg * 4 + r, cp),
                    (u64)(pk[r] | (nb[r] << 16)));   // ctr = 0 in high dword
        }
    }

    // ---- c0 -> registers ----
    float cst[4];
#pragma unroll
    for (int r = 0; r < 4; ++r)
        cst[r] = c0[(size_t)(g * 16 + kg * 4 + r) * H_N + col];

    float hnew[4] = {};
    unsigned dead = 0;

    __syncthreads();

    const char* p_xg0 = out + (size_t)g * 16384 + (size_t)tc * 512 + (size_t)lane * 8;           // i
    const char* p_xg1 = p_xg0 + 16 * 512;                                                         // f
    const char* p_xg2 = out + HY_BYTES + (size_t)g * 16384 + (size_t)tc * 512 + (size_t)lane * 8; // g
    const char* p_xg3 = p_xg2 + 16 * 512;                                                         // o
    char* st_h = out + (size_t)(g * 16 + kg * 4) * 1024 + (size_t)col * 4;
    char* st_c = st_h + HY_BYTES;

    const int amask = (l15 & 7) << 4;
    const int pvwv0 = (kg >> 1);       // wave offset within slice pair
    const int pvcp  = (kg & 1) * 4;

    s16x4 xg[4];
    u64 pv[4][4];

#define XG_LOAD(T) do {                                                       \
        const size_t _o = ((size_t)(T) << 16);                                \
        xg[0] = ntl4(p_xg0 + _o);  xg[1] = ntl4(p_xg1 + _o);                  \
        xg[2] = ntl4(p_xg2 + _o);  xg[3] = ntl4(p_xg3 + _o);                  \
    } while (0)

#define PV_LOAD(PAR) do {                                                     \
        _Pragma("unroll")                                                     \
        for (int s = 0; s < 4; ++s) {                                         \
            const u64* _pp = exch + PV_IDX(PAR, b ^ 4, 2 * s + pvwv0,         \
                                           l15, pvcp);                        \
            pv[s][0] = ald(_pp);     pv[s][1] = ald(_pp + 1);                 \
            pv[s][2] = ald(_pp + 2); pv[s][3] = ald(_pp + 3);                 \
        }                                                                     \
    } while (0)

#define PV_BAD(T, BAD) do {                                                   \
        BAD = 0;                                                              \
        _Pragma("unroll")                                                     \
        for (int s = 0; s < 4; ++s)                                           \
            _Pragma("unroll")                                                 \
            for (int i = 0; i < 4; ++i)                                       \
                BAD |= (unsigned)(pv[s][i] >> 32) ^ (unsigned)(T);            \
    } while (0)

    XG_LOAD(0);
    asm volatile("s_waitcnt vmcnt(0)" ::: "memory");

#define STEP(PAR, T) do {                                                     \
        /* 1. speculative partner-frag loads (published ~a barrier ago) */    \
        PV_LOAD(PAR);                                                         \
        /* 2. h,c outputs of step T-1 (cached stores; never waited on) */     \
        if ((T) > 0) {                                                        \
            char* _hp = st_h + ((size_t)((T) - 1) << 16);                     \
            char* _cp = st_c + ((size_t)((T) - 1) << 16);                     \
            _Pragma("unroll")                                                 \
            for (int r = 0; r < 4; ++r) {                                     \
                *(float*)(_hp + r * 1024) = hnew[r];                          \
                *(float*)(_cp + r * 1024) = cst[r];                           \
            }                                                                 \
        }                                                                     \
        /* 3. acc <- pre-scaled xg fragment */                                \
        f32x4 acc[4];                                                         \
        _Pragma("unroll")                                                     \
        for (int q = 0; q < 4; ++q) {                                         \
            acc[q][0] = bf2f(xg[q][0]); acc[q][1] = bf2f(xg[q][1]);           \
            acc[q][2] = bf2f(xg[q][2]); acc[q][3] = bf2f(xg[q][3]);           \
        }                                                                     \
        /* 4. own-half k-slices (own h in hlds; W f,g from LDS) */            \
        _Pragma("unroll")                                                     \
        for (int s = 0; s < 4; ++s) {                                         \
            const int ks = oks + s;                                           \
            s16x8 av = *(const s16x8*)((const char*)hlds[PAR] +               \
                            l15 * 256 + ((s * 64 + kg * 16) ^ amask));        \
            s16x8 b1 = *(const s16x8*)(&wlds[((0 * 8 + w) * 8 + ks) * 512 + lane * 8]); \
            s16x8 b2 = *(const s16x8*)(&wlds[((1 * 8 + w) * 8 + ks) * 512 + lane * 8]); \
            acc[0] = MFMA(av, wreg0[ks], acc[0]);                             \
            acc[1] = MFMA(av, b1, acc[1]);                                    \
            acc[2] = MFMA(av, b2, acc[2]);                                    \
            acc[3] = MFMA(av, wreg3[ks], acc[3]);                             \
        }                                                                     \
        /* 5. validate embedded ctrs (loads landed under own MFMA) */         \
        {                                                                     \
            unsigned bad;                                                     \
            PV_BAD(T, bad);                                                   \
            if (!__all(bad == 0) && !dead) {                                  \
                unsigned spins = 0;                                           \
                for (;;) {                                                    \
                    PV_LOAD(PAR);                                             \
                    PV_BAD(T, bad);                                           \
                    if (__all(bad == 0)) break;                               \
                    __builtin_amdgcn_s_sleep(1);                              \
                    if (++spins > 16384u) { dead = 1; break; }                \
                }                                                             \
            }                                                                 \
        }                                                                     \
        /* 6. partner-half k-slices: frags straight from pv */                \
        _Pragma("unroll")                                                     \
        for (int s = 0; s < 4; ++s) {                                         \
            const int ks = pks + s;                                           \
            struct { u64 a, c; } pr;                                          \
            pr.a = (u64)(unsigned)pv[s][0] | ((u64)(unsigned)pv[s][1] << 32); \
            pr.c = (u64)(unsigned)pv[s][2] | ((u64)(unsigned)pv[s][3] << 32); \
            s16x8 av = __builtin_bit_cast(s16x8, pr);                         \
            s16x8 b1 = *(const s16x8*)(&wlds[((0 * 8 + w) * 8 + ks) * 512 + lane * 8]); \
            s16x8 b2 = *(const s16x8*)(&wlds[((1 * 8 + w) * 8 + ks) * 512 + lane * 8]); \
            acc[0] = MFMA(av, wreg0[ks], acc[0]);                             \
            acc[1] = MFMA(av, b1, acc[1]);                                    \
            acc[2] = MFMA(av, b2, acc[2]);                                    \
            acc[3] = MFMA(av, wreg3[ks], acc[3]);                             \
        }                                                                     \
        /* 7. activations */                                                  \
        unsigned pk[4];                                                       \
        _Pragma("unroll")                                                     \
        for (int r = 0; r < 4; ++r) {                                         \
            float Ei = e2c(acc[0][r]);                                        \
            float Ef = e2c(acc[1][r]);                                        \
            float Eg = e2c(acc[2][r]);                                        \
            float Eo = e2c(acc[3][r]);                                        \
            float ai = 1.0f + Ei, af = 1.0f + Ef;                             \
            float ag = 1.0f + Eg, ao = 1.0f + Eo;                             \
            float r1 = __builtin_amdgcn_rcpf(ai * af);                        \
            float gi = r1 * af;                                               \
            float gf = r1 * ai;                                               \
            float r2 = __builtin_amdgcn_rcpf(ag * ao);                        \
            float go = r2 * ag;                                               \
            float tg = 2.0f * (r2 * ao) - 1.0f;                               \
            float c  = gf * cst[r] + gi * tg;                                 \
            cst[r] = c;                                                       \
            float Ec = e2c(-C2 * c);                                          \
            float tc_ = 2.0f * __builtin_amdgcn_rcpf(1.0f + Ec) - 1.0f;       \
            hnew[r] = go * tc_;                                               \
            pk[r] = (unsigned)(unsigned short)f2bf(hnew[r]);                  \
        }                                                                     \
        /* 8. publish h(T) in A-layout with embedded ctr (fire-and-forget) */ \
        if ((T) + 1 < T_N) {                                                  \
            unsigned nb[4];                                                   \
            _Pragma("unroll")                                                 \
            for (int r = 0; r < 4; ++r) nb[r] = __shfl_xor(pk[r], 1, 64);     \
            if (!(l15 & 1)) {                                                 \
                int cp = l15 >> 1;             /* FIX: within-wave colpair */ \
                u64 cb = ((u64)(unsigned)((T) + 1)) << 32;                    \
                _Pragma("unroll")                                             \
                for (int r = 0; r < 4; ++r)                                   \
                    ast(exch + PV_IDX((PAR) ^ 1, b, w, kg * 4 + r, cp),       \
                        cb | (u64)(pk[r] | (nb[r] << 16)));                   \
            }                                                                 \
        }                                                                     \
        /* 9. own-half h -> hlds[PAR^1] */                                    \
        _Pragma("unroll")                                                     \
        for (int r = 0; r < 4; ++r) {                                         \
            int row = kg * 4 + r;                                             \
            int byte = row * 256 + ((2 * lc) ^ ((row & 7) << 4));             \
            *(short*)((char*)hlds[(PAR) ^ 1] + byte) = (short)pk[r];          \
        }                                                                     \
        /* 10. next step's xg */                                              \
        if ((T) + 1 < T_N) XG_LOAD((T) + 1);                                  \
        /* 11. barrier: own-half hlds visible */                              \
        asm volatile("s_waitcnt lgkmcnt(0)" ::: "memory");                    \
        __builtin_amdgcn_s_barrier();                                         \
        asm volatile("" ::: "memory");                                        \
    } while (0)

#pragma unroll 1
    for (int tt = 0; tt < T_N; tt += 2) {
        STEP(0, tt);
        STEP(1, tt + 1);
    }

    // epilogue: h,c of last step + final (hy[-1], cy[-1]) for my cols
    {
        char* hp = st_h + ((size_t)(T_N - 1) << 16);
        char* cp = st_c + ((size_t)(T_N - 1) << 16);
        char* fh = out + 2 * HY_BYTES + (size_t)(g * 16 + kg * 4) * 1024 + (size_t)col * 4;
        char* fc = fh + 65536;
#pragma unroll
        for (int r = 0; r < 4; ++r) {
            *(float*)(hp + r * 1024) = hnew[r];
            *(float*)(cp + r * 1024) = cst[r];
            *(float*)(fh + r * 1024) = hnew[r];
            *(float*)(fc + r * 1024) = cst[r];
        }
    }
#undef STEP
#undef XG_LOAD
#undef PV_LOAD
#undef PV_BAD
}

// ---------------------------------------------------------------------------
// Fallback (WS_V1 <= ws < WS_V3): round-10 kernel (proven 5.95 ms).
// ---------------------------------------------------------------------------
__global__ __launch_bounds__(512)
__attribute__((amdgpu_waves_per_eu(2, 2)))
void lstm_rec8(
        const float* __restrict__ h0, const float* __restrict__ c0,
        const float* __restrict__ w_hh, char* __restrict__ out,
        char* __restrict__ ws)
{
    const int b    = blockIdx.x;
    const int g    = b & 3;
    const int hf   = b >> 2;
    const int tid  = threadIdx.x;
    const int w    = tid >> 6;
    const int lane = tid & 63;
    const int l15  = lane & 15;
    const int kg   = lane >> 4;

    const int tc   = hf * 8 + w;
    const int ptc  = (hf ^ 1) * 8 + w;
    const int col  = tc * 16 + l15;
    const int pcol = ptc * 16 + l15;

    __shared__ short hlds[2][4096];

    u64* exch = (u64*)ws;
    unsigned* flags = (unsigned*)(ws + EXCH_BYTES);
    const size_t myx = ((size_t)b * 8 + w) * 64 + lane;
    const size_t pbx = ((size_t)(b ^ 4) * 8 + w) * 64 + lane;
    unsigned* myflag = &flags[b * 8 + w];
    unsigned* pflag  = &flags[(b ^ 4) * 8 + w];

    s16x8 wreg[4][8];
#pragma unroll
    for (int q = 0; q < 4; ++q) {
        const int tau = 16 * q + tc;
        const float scale = (q == 2) ? -C2 : -C1;
        const float* wp = w_hh + (size_t)(tau * 16 + l15) * H_N;
#pragma unroll
        for (int ks = 0; ks < 8; ++ks) {
            const float* p = wp + ks * 32 + kg * 8;
            f32x4 w0 = *(const f32x4*)(p);
            f32x4 w1 = *(const f32x4*)(p + 4);
            s16x8 v;
            v[0]=f2bf(scale*w0[0]); v[1]=f2bf(scale*w0[1]);
            v[2]=f2bf(scale*w0[2]); v[3]=f2bf(scale*w0[3]);
            v[4]=f2bf(scale*w1[0]); v[5]=f2bf(scale*w1[1]);
            v[6]=f2bf(scale*w1[2]); v[7]=f2bf(scale*w1[3]);
            wreg[q][ks] = v;
        }
    }

    {
        const int row  = tid >> 5;
        const int col0 = (tid & 31) * 8;
        const float* hp = h0 + (size_t)(g * 16 + row) * H_N + col0;
        const int sw = (row & 7) << 4;
#pragma unroll
        for (int j = 0; j < 8; ++j) {
            int byte = row * 512 + ((2 * (col0 + j)) ^ sw);
            *(short*)((char*)hlds[0] + byte) = f2bf(hp[j]);
        }
    }

    float cst[4];
#pragma unroll
    for (int r = 0; r < 4; ++r)
        cst[r] = c0[(size_t)(g * 16 + kg * 4 + r) * H_N + col];

    float hnew[4] = {};
    unsigned dead = 0;

    __syncthreads();

    const char* p_xg0 = out + (size_t)g * 16384 + (size_t)tc * 512 + (size_t)lane * 8;
    const char* p_xg1 = p_xg0 + 16 * 512;
    const char* p_xg2 = out + HY_BYTES + (size_t)g * 16384 + (size_t)tc * 512 + (size_t)lane * 8;
    const char* p_xg3 = p_xg2 + 16 * 512;
    char* st_h = out + (size_t)(g * 16 + kg * 4) * 1024 + (size_t)col * 4;
    char* st_c = st_h + HY_BYTES;

    const int amask = (l15 & 7) << 4;

    s16x4 xg[4];

#define XG_LOAD(T) do {                                                       \
        const size_t _o = ((size_t)(T) << 16);                                \
        xg[0] = ntl4(p_xg0 + _o);  xg[1] = ntl4(p_xg1 + _o);                  \
        xg[2] = ntl4(p_xg2 + _o);  xg[3] = ntl4(p_xg3 + _o);                  \
    } while (0)

    XG_LOAD(0);
    asm volatile("s_waitcnt vmcnt(0)" ::: "memory");

#define STEP(PAR, T) do {                                                     \
        if ((T) > 0) {                                                        \
            char* _hp = st_h + ((size_t)((T) - 1) << 16);                     \
            char* _cp = st_c + ((size_t)((T) - 1) << 16);                     \
            _Pragma("unroll")                                                 \
            for (int r = 0; r < 4; ++r) {                                     \
                *(float*)(_hp + r * 1024) = hnew[r];                          \
                *(float*)(_cp + r * 1024) = cst[r];                           \
            }                                                                 \
        }                                                                     \
        unsigned fv = __hip_atomic_load(pflag, __ATOMIC_RELAXED,              \
                                        __HIP_MEMORY_SCOPE_AGENT);            \
        f32x4 acc[4];                                                         \
        _Pragma("unroll")                                                     \
        for (int q = 0; q < 4; ++q) {                                         \
            acc[q][0] = bf2f(xg[q][0]); acc[q][1] = bf2f(xg[q][1]);           \
            acc[q][2] = bf2f(xg[q][2]); acc[q][3] = bf2f(xg[q][3]);           \
        }                                                                     \
        _Pragma("unroll")                                                     \
        for (int ks = 0; ks < 8; ++ks) {                                      \
            s16x8 av = *(const s16x8*)((const char*)hlds[PAR] +               \
                            l15 * 512 + ((ks * 64 + kg * 16) ^ amask));       \
            acc[0] = MFMA(av, wreg[0][ks], acc[0]);                           \
            acc[1] = MFMA(av, wreg[1][ks], acc[1]);                           \
            acc[2] = MFMA(av, wreg[2][ks], acc[2]);                           \
            acc[3] = MFMA(av, wreg[3][ks], acc[3]);                           \
        }                                                                     \
        unsigned pk0, pk1;                                                    \
        {                                                                     \
            _Pragma("unroll")                                                 \
            for (int r = 0; r < 4; ++r) {                                     \
                float Ei = e2c(acc[0][r]);                                    \
                float Ef = e2c(acc[1][r]);                                    \
                float Eg = e2c(acc[2][r]);                                    \
                float Eo = e2c(acc[3][r]);                                    \
                float ai = 1.0f + Ei, af = 1.0f + Ef;                         \
                float ag = 1.0f + Eg, ao = 1.0f + Eo;                         \
                float r1 = __builtin_amdgcn_rcpf(ai * af);                    \
                float gi = r1 * af;                                           \
                float gf = r1 * ai;                                           \
                float r2 = __builtin_amdgcn_rcpf(ag * ao);                    \
                float go = r2 * ag;                                           \
                float tg = 2.0f * (r2 * ao) - 1.0f;                           \
                float c  = gf * cst[r] + gi * tg;                             \
                cst[r] = c;                                                   \
                float Ec = e2c(-C2 * c);                                      \
                float tc_ = 2.0f * __builtin_amdgcn_rcpf(1.0f + Ec) - 1.0f;   \
                hnew[r] = go * tc_;                                           \
            }                                                                 \
            unsigned s0 = (unsigned short)f2bf(hnew[0]);                      \
            unsigned s1 = (unsigned short)f2bf(hnew[1]);                      \
            unsigned s2 = (unsigned short)f2bf(hnew[2]);                      \
            unsigned s3 = (unsigned short)f2bf(hnew[3]);                      \
            pk0 = s0 | (s1 << 16);                                            \
            pk1 = s2 | (s3 << 16);                                            \
            _Pragma("unroll")                                                 \
            for (int r = 0; r < 4; ++r) {                                     \
                int row = kg * 4 + r;                                         \
                int byte = row * 512 + ((2 * col) ^ ((row & 7) << 4));        \
                unsigned v = (r < 2) ? pk0 : pk1;                             \
                *(short*)((char*)hlds[(PAR) ^ 1] + byte) =                    \
                    (short)((r & 1) ? (v >> 16) : v);                         \
            }                                                                 \
        }                                                                     \
        if ((T) + 1 < T_N) {                                                  \
            unsigned long long val = ((unsigned long long)pk1 << 32) | pk0;   \
            __hip_atomic_store(exch + (size_t)(PAR) * 4096 + myx, val,        \
                               __ATOMIC_RELAXED, __HIP_MEMORY_SCOPE_AGENT);   \
            asm volatile("s_waitcnt vmcnt(0)" ::: "memory");                  \
            if (lane == 0)                                                    \
                __hip_atomic_store(myflag, (unsigned)((T) + 1),               \
                                   __ATOMIC_RELAXED,                          \
                                   __HIP_MEMORY_SCOPE_AGENT);                 \
            XG_LOAD((T) + 1);                                                 \
            if (fv < (unsigned)((T) + 1) && !dead) {                          \
                unsigned spins = 0;                                           \
                while (__hip_atomic_load(pflag, __ATOMIC_RELAXED,             \
                                         __HIP_MEMORY_SCOPE_AGENT)           \
                       < (unsigned)((T) + 1)) {                               \
                    __builtin_amdgcn_s_sleep(1);                              \
                    if (++spins > 16384u) { dead = 1; break; }                \
                }                                                             \
            }                                                                 \
            unsigned long long pvv = __hip_atomic_load(                       \
                exch + (size_t)(PAR) * 4096 + pbx,                            \
                __ATOMIC_RELAXED, __HIP_MEMORY_SCOPE_AGENT);                  \
            _Pragma("unroll")                                                 \
            for (int r = 0; r < 4; ++r) {                                     \
                int row = kg * 4 + r;                                         \
                int byte = row * 512 + ((2 * pcol) ^ ((row & 7) << 4));       \
                *(short*)((char*)hlds[(PAR) ^ 1] + byte) =                    \
                    (short)(pvv >> (16 * r));                                 \
            }                                                                 \
        }                                                                     \
        asm volatile("s_waitcnt lgkmcnt(0)" ::: "memory");                    \
        __builtin_amdgcn_s_barrier();                                         \
        asm volatile("" ::: "memory");                                        \
    } while (0)

#pragma unroll 1
    for (int tt = 0; tt < T_N; tt += 2) {
        STEP(0, tt);
        STEP(1, tt + 1);
    }

    {
        char* hp = st_h + ((size_t)(T_N - 1) << 16);
        char* cp = st_c + ((size_t)(T_N - 1) << 16);
        char* fh = out + 2 * HY_BYTES + (size_t)(g * 16 + kg * 4) * 1024 + (size_t)col * 4;
        char* fc = fh + 65536;
#pragma unroll
        for (int r = 0; r < 4; ++r) {
            *(float*)(hp + r * 1024) = hnew[r];
            *(float*)(cp + r * 1024) = cst[r];
            *(float*)(fh + r * 1024) = hnew[r];
            *(float*)(fc + r * 1024) = cst[r];
        }
    }
#undef STEP
#undef XG_LOAD
}

extern "C" void kernel_launch(void* const* d_in, const int* in_sizes, int n_in,
                              void* d_out, int out_size, void* d_ws, size_t ws_size,
                              hipStream_t stream) {
    (void)in_sizes; (void)n_in; (void)out_size;
    const float* x    = (const float*)d_in[0];
    const float* h0   = (const float*)d_in[1];
    const float* c0   = (const float*)d_in[2];
    const float* w_ih = (const float*)d_in[3];
    const float* w_hh = (const float*)d_in[4];
    const float* b_ih = (const float*)d_in[5];
    const float* b_hh = (const float*)d_in[6];
    char* out = (char*)d_out;

    if (ws_size >= WS_V3) {
        // exact-ctr matching: stale replay data is identical (deterministic)
        // and poison never matches -> no zeroing kernel needed
        xg_gemm<<<dim3(1024, 4), 512, 0, stream>>>(x, w_ih, b_ih, b_hh, out);
        lstm_rec8v3<<<8, 512, 0, stream>>>(h0, c0, w_hh, out, (char*)d_ws);
    } else {
        zero_flags<<<1, 64, 0, stream>>>((char*)d_ws);
        xg_gemm<<<dim3(1024, 4), 512, 0, stream>>>(x, w_ih, b_ih, b_hh, out);
        lstm_rec8<<<8, 512, 0, stream>>>(h0, c0, w_hh, out, (char*)d_ws);
    }
}

// Round 14
// 5141.435 us; speedup vs baseline: 1.3920x; 1.3920x over previous
//
#include <hip/hip_runtime.h>

typedef short s16x8 __attribute__((ext_vector_type(8)));
typedef short s16x4 __attribute__((ext_vector_type(4)));
typedef float f32x4 __attribute__((ext_vector_type(4)));
typedef unsigned long long u64;

#define T_N 2048
#define B_N 64
#define H_N 256
#define I_N 256
#define HY_BYTES ((size_t)134217728)   // 4 * T * B * H
// v2/v4: exch u64[2 parity][8 wg][8 wave][64 lane][2] = 128 KB, data|ctr fused
#define WS_V2 131072
// v1 (r10): exch 64KB + u32 flags[64]
#define EXCH_BYTES 65536
#define WS_V1 (EXCH_BYTES + 256)

static __device__ __forceinline__ short f2bf(float f) {
    unsigned u = __builtin_bit_cast(unsigned, f);
    u += 0x7FFFu + ((u >> 16) & 1u);   // RNE
    return (short)(u >> 16);
}
static __device__ __forceinline__ float bf2f(short h) {
    unsigned u = ((unsigned)(unsigned short)h) << 16;
    return __builtin_bit_cast(float, u);
}
static __device__ __forceinline__ float e2c(float a) {
    return __builtin_amdgcn_exp2f(fminf(a, 126.0f));
}
static __device__ __forceinline__ s16x4 ntl4(const void* p) {
    return __builtin_nontemporal_load((const s16x4*)p);
}

#define C1 1.44269504088896340f   // log2(e)
#define C2 2.88539008177792681f   // 2*log2(e)

#define MFMA(a, b, c) __builtin_amdgcn_mfma_f32_16x16x32_bf16(a, b, c, 0, 0, 0)

// ---------------------------------------------------------------------------
// zero flags (v1 fallback path only; ws not re-poisoned per replay)
// ---------------------------------------------------------------------------
__global__ void zero_flags(char* __restrict__ ws) {
    if (threadIdx.x < 64) ((unsigned*)(ws + EXCH_BYTES))[threadIdx.x] = 0u;
}

// ---------------------------------------------------------------------------
// Phase 1: xg = x @ w_ih^T + bias, pre-scaled by -C1 (i,f,o) / -C2 (g),
// bf16 in MFMA C-fragment layout inside d_out (unchanged).
// ---------------------------------------------------------------------------
__global__ __launch_bounds__(512) void xg_gemm(
        const float* __restrict__ x, const float* __restrict__ w_ih,
        const float* __restrict__ b_ih, const float* __restrict__ b_hh,
        char* __restrict__ out)
{
    const int tid  = threadIdx.x;
    const int wave = tid >> 6;
    const int lane = tid & 63;
    const int l15  = lane & 15;
    const int kg   = lane >> 4;

    __shared__ short Blds[8192];

    const int m16 = blockIdx.x * 8 + wave;
    const int by  = blockIdx.y;
    const int n0  = by * 256;

    const float* xrow = x + (size_t)(m16 * 16 + l15) * I_N;

    f32x4 acc[16] = {};

#pragma unroll 1
    for (int ks = 0; ks < 8; ++ks) {
        __syncthreads();
#pragma unroll
        for (int h = 0; h < 2; ++h) {
            int nl = (tid >> 2) + h * 128;
            int c  = tid & 3;
            const float* wp = w_ih + (size_t)(n0 + nl) * I_N + ks * 32 + c * 8;
            f32x4 w0 = *(const f32x4*)(wp);
            f32x4 w1 = *(const f32x4*)(wp + 4);
            s16x8 bv;
            bv[0]=f2bf(w0[0]); bv[1]=f2bf(w0[1]); bv[2]=f2bf(w0[2]); bv[3]=f2bf(w0[3]);
            bv[4]=f2bf(w1[0]); bv[5]=f2bf(w1[1]); bv[6]=f2bf(w1[2]); bv[7]=f2bf(w1[3]);
            int dt = nl >> 4;
            int lp = (nl & 15) + 16 * c;
            *(s16x8*)(&Blds[(dt * 64 + lp) * 8]) = bv;
        }
        __syncthreads();
        const float* ap = xrow + ks * 32 + kg * 8;
        f32x4 a0 = *(const f32x4*)(ap);
        f32x4 a1 = *(const f32x4*)(ap + 4);
        s16x8 av;
        av[0]=f2bf(a0[0]); av[1]=f2bf(a0[1]); av[2]=f2bf(a0[2]); av[3]=f2bf(a0[3]);
        av[4]=f2bf(a1[0]); av[5]=f2bf(a1[1]); av[6]=f2bf(a1[2]); av[7]=f2bf(a1[3]);
#pragma unroll
        for (int dt = 0; dt < 16; ++dt) {
            s16x8 bv = *(const s16x8*)(&Blds[(dt * 64 + lane) * 8]);
            acc[dt] = MFMA(av, bv, acc[dt]);
        }
    }

    const int t = m16 >> 2;
    const int g = m16 & 3;
#pragma unroll
    for (int dt = 0; dt < 16; ++dt) {
        int tau = by * 16 + dt;
        int n   = tau * 16 + l15;
        float bias = b_ih[n] + b_hh[n];
        float scale = ((tau >> 4) == 2) ? -C2 : -C1;
        size_t base = (tau < 32)
            ? ((size_t)t * 65536 + (size_t)g * 16384 + (size_t)tau * 512)
            : (HY_BYTES + (size_t)t * 65536 + (size_t)g * 16384 + (size_t)(tau - 32) * 512);
        s16x4 o;
        o[0] = f2bf(scale * (acc[dt][0] + bias));
        o[1] = f2bf(scale * (acc[dt][1] + bias));
        o[2] = f2bf(scale * (acc[dt][2] + bias));
        o[3] = f2bf(scale * (acc[dt][3] + bias));
        *(s16x4*)(out + base + lane * 8) = o;
    }
}

// ---------------------------------------------------------------------------
// Phase 2 v4: v2 (4.76 ms, data-embedded counters) with the step-end latency
// chain reordered.  v2 defect: pv loads were issued AFTER the xg prefetch, so
// the counted wait retiring them also drained the 4 fresh HBM xg loads.
// v4 order: publish -> pv loads -> h/c stores (moved into this gap) -> own
// hlds stage -> xg prefetch (BEHIND pv in the vmem queue) -> pv check.
// The pv wait retires only the pv loads; ~150 cyc of fire-and-forget issue
// covers part of the L3 round trip and absorbs partner skew.
// Protocol/layout identical to v2.  Sticky bounded retry: never hangs.
// ---------------------------------------------------------------------------
__global__ __launch_bounds__(512)
__attribute__((amdgpu_waves_per_eu(2, 2)))
void lstm_rec8v4(
        const float* __restrict__ h0, const float* __restrict__ c0,
        const float* __restrict__ w_hh, char* __restrict__ out,
        char* __restrict__ ws)
{
    const int b    = blockIdx.x;       // 0..7
    const int g    = b & 3;
    const int hf   = b >> 2;
    const int tid  = threadIdx.x;
    const int w    = tid >> 6;
    const int lane = tid & 63;
    const int l15  = lane & 15;
    const int kg   = lane >> 4;

    const int tc   = hf * 8 + w;       // my col-tile (0..15)
    const int ptc  = (hf ^ 1) * 8 + w; // partner col-tile staged by this wave
    const int col  = tc * 16 + l15;
    const int pcol = ptc * 16 + l15;

    __shared__ short hlds[2][4096];    // double-buffered 16x256 bf16, swizzled

    u64* exch = (u64*)ws;
    // [parity][wg][wave][lane][2]: parity stride 8192 u64
    const size_t myx = (size_t)b * 1024 + (size_t)w * 128 + (size_t)lane * 2;
    const size_t pbx = (size_t)(b ^ 4) * 1024 + (size_t)w * 128 + (size_t)lane * 2;

    // ---- W fragments: 4 gate tiles, pre-scaled, register-resident ----
    s16x8 wreg[4][8];
#pragma unroll
    for (int q = 0; q < 4; ++q) {
        const int tau = 16 * q + tc;
        const float scale = (q == 2) ? -C2 : -C1;
        const float* wp = w_hh + (size_t)(tau * 16 + l15) * H_N;
#pragma unroll
        for (int ks = 0; ks < 8; ++ks) {
            const float* p = wp + ks * 32 + kg * 8;
            f32x4 w0 = *(const f32x4*)(p);
            f32x4 w1 = *(const f32x4*)(p + 4);
            s16x8 v;
            v[0]=f2bf(scale*w0[0]); v[1]=f2bf(scale*w0[1]);
            v[2]=f2bf(scale*w0[2]); v[3]=f2bf(scale*w0[3]);
            v[4]=f2bf(scale*w1[0]); v[5]=f2bf(scale*w1[1]);
            v[6]=f2bf(scale*w1[2]); v[7]=f2bf(scale*w1[3]);
            wreg[q][ks] = v;
        }
    }

    // ---- h0 -> hlds[0] (full 256 cols, bf16, XOR swizzle per row) ----
    {
        const int row  = tid >> 5;
        const int col0 = (tid & 31) * 8;
        const float* hp = h0 + (size_t)(g * 16 + row) * H_N + col0;
        const int sw = (row & 7) << 4;
#pragma unroll
        for (int j = 0; j < 8; ++j) {
            int byte = row * 512 + ((2 * (col0 + j)) ^ sw);
            *(short*)((char*)hlds[0] + byte) = f2bf(hp[j]);
        }
    }

    // ---- c0 -> registers (my cols only) ----
    float cst[4];
#pragma unroll
    for (int r = 0; r < 4; ++r)
        cst[r] = c0[(size_t)(g * 16 + kg * 4 + r) * H_N + col];

    float hnew[4] = {};
    unsigned dead = 0;    // sticky poll-timeout marker

    __syncthreads();

    const char* p_xg0 = out + (size_t)g * 16384 + (size_t)tc * 512 + (size_t)lane * 8;           // i
    const char* p_xg1 = p_xg0 + 16 * 512;                                                         // f
    const char* p_xg2 = out + HY_BYTES + (size_t)g * 16384 + (size_t)tc * 512 + (size_t)lane * 8; // g
    const char* p_xg3 = p_xg2 + 16 * 512;                                                         // o
    char* st_h = out + (size_t)(g * 16 + kg * 4) * 1024 + (size_t)col * 4;
    char* st_c = st_h + HY_BYTES;

    const int amask = (l15 & 7) << 4;

    s16x4 xg[4];

#define XG_LOAD(T) do {                                                       \
        const size_t _o = ((size_t)(T) << 16);                                \
        xg[0] = ntl4(p_xg0 + _o);  xg[1] = ntl4(p_xg1 + _o);                  \
        xg[2] = ntl4(p_xg2 + _o);  xg[3] = ntl4(p_xg3 + _o);                  \
    } while (0)

    XG_LOAD(0);
    asm volatile("s_waitcnt vmcnt(0)" ::: "memory");

#define STEP(PAR, T) do {                                                     \
        /* 1. acc <- pre-scaled xg fragment (identical layout) */             \
        f32x4 acc[4];                                                         \
        _Pragma("unroll")                                                     \
        for (int q = 0; q < 4; ++q) {                                         \
            acc[q][0] = bf2f(xg[q][0]); acc[q][1] = bf2f(xg[q][1]);           \
            acc[q][2] = bf2f(xg[q][2]); acc[q][3] = bf2f(xg[q][3]);           \
        }                                                                     \
        /* 2. gates += h_{T-1} @ (scaled W)^T  (full k=256; W in regs) */     \
        _Pragma("unroll")                                                     \
        for (int ks = 0; ks < 8; ++ks) {                                      \
            s16x8 av = *(const s16x8*)((const char*)hlds[PAR] +               \
                            l15 * 512 + ((ks * 64 + kg * 16) ^ amask));       \
            acc[0] = MFMA(av, wreg[0][ks], acc[0]);                           \
            acc[1] = MFMA(av, wreg[1][ks], acc[1]);                           \
            acc[2] = MFMA(av, wreg[2][ks], acc[2]);                           \
            acc[3] = MFMA(av, wreg[3][ks], acc[3]);                           \
        }                                                                     \
        /* 3. activations (exp2 fed directly by pre-scaled gates) */          \
        unsigned pk0, pk1;                                                    \
        {                                                                     \
            _Pragma("unroll")                                                 \
            for (int r = 0; r < 4; ++r) {                                     \
                float Ei = e2c(acc[0][r]);                                    \
                float Ef = e2c(acc[1][r]);                                    \
                float Eg = e2c(acc[2][r]);                                    \
                float Eo = e2c(acc[3][r]);                                    \
                float ai = 1.0f + Ei, af = 1.0f + Ef;                         \
                float ag = 1.0f + Eg, ao = 1.0f + Eo;                         \
                float r1 = __builtin_amdgcn_rcpf(ai * af);                    \
                float gi = r1 * af;                                           \
                float gf = r1 * ai;                                           \
                float r2 = __builtin_amdgcn_rcpf(ag * ao);                    \
                float go = r2 * ag;                                           \
                float tg = 2.0f * (r2 * ao) - 1.0f;                           \
                float c  = gf * cst[r] + gi * tg;                             \
                cst[r] = c;                                                   \
                float Ec = e2c(-C2 * c);                                      \
                float tc_ = 2.0f * __builtin_amdgcn_rcpf(1.0f + Ec) - 1.0f;   \
                hnew[r] = go * tc_;                                           \
            }                                                                 \
            unsigned s0 = (unsigned short)f2bf(hnew[0]);                      \
            unsigned s1 = (unsigned short)f2bf(hnew[1]);                      \
            unsigned s2 = (unsigned short)f2bf(hnew[2]);                      \
            unsigned s3 = (unsigned short)f2bf(hnew[3]);                      \
            pk0 = s0 | (s1 << 16);                                            \
            pk1 = s2 | (s3 << 16);                                            \
        }                                                                     \
        u64 v0 = 0, v1 = 0;                                                   \
        if ((T) + 1 < T_N) {                                                  \
            /* 4. publish data|ctr fused — fire and forget */                 \
            u64 c64 = ((u64)(unsigned)((T) + 1)) << 32;                       \
            u64* _m = exch + (size_t)(PAR) * 8192 + myx;                      \
            __hip_atomic_store(_m,     (u64)pk0 | c64,                        \
                               __ATOMIC_RELAXED, __HIP_MEMORY_SCOPE_AGENT);   \
            __hip_atomic_store(_m + 1, (u64)pk1 | c64,                        \
                               __ATOMIC_RELAXED, __HIP_MEMORY_SCOPE_AGENT);   \
            /* 5. speculative pv loads — issued EARLY, ahead of xg */         \
            const u64* _p = exch + (size_t)(PAR) * 8192 + pbx;                \
            v0 = __hip_atomic_load(_p,     __ATOMIC_RELAXED,                  \
                                   __HIP_MEMORY_SCOPE_AGENT);                 \
            v1 = __hip_atomic_load(_p + 1, __ATOMIC_RELAXED,                  \
                                   __HIP_MEMORY_SCOPE_AGENT);                 \
        }                                                                     \
        /* 6. h,c of THIS step -> global (fire-and-forget, fills the gap) */  \
        {                                                                     \
            char* _hp = st_h + ((size_t)(T) << 16);                           \
            char* _cp = st_c + ((size_t)(T) << 16);                           \
            _Pragma("unroll")                                                 \
            for (int r = 0; r < 4; ++r) {                                     \
                *(float*)(_hp + r * 1024) = hnew[r];                          \
                *(float*)(_cp + r * 1024) = cst[r];                           \
            }                                                                 \
        }                                                                     \
        /* 7. own-half h -> hlds[PAR^1] */                                    \
        _Pragma("unroll")                                                     \
        for (int r = 0; r < 4; ++r) {                                         \
            int row = kg * 4 + r;                                             \
            int byte = row * 512 + ((2 * col) ^ ((row & 7) << 4));            \
            unsigned v = (r < 2) ? pk0 : pk1;                                 \
            *(short*)((char*)hlds[(PAR) ^ 1] + byte) =                        \
                (short)((r & 1) ? (v >> 16) : v);                             \
        }                                                                     \
        if ((T) + 1 < T_N) {                                                  \
            /* 8. xg prefetch — behind pv in the vmem queue */                \
            XG_LOAD((T) + 1);                                                 \
            /* 9. check embedded ctrs; retry only if stale */                 \
            const unsigned tgt = (unsigned)((T) + 1);                         \
            int ok = ((unsigned)(v0 >> 32) == tgt) &                          \
                     ((unsigned)(v1 >> 32) == tgt);                           \
            if (!__all(ok) && !dead) {                                        \
                const u64* _p = exch + (size_t)(PAR) * 8192 + pbx;            \
                unsigned spins = 0;                                           \
                for (;;) {                                                    \
                    v0 = __hip_atomic_load(_p,     __ATOMIC_RELAXED,          \
                                           __HIP_MEMORY_SCOPE_AGENT);         \
                    v1 = __hip_atomic_load(_p + 1, __ATOMIC_RELAXED,          \
                                           __HIP_MEMORY_SCOPE_AGENT);         \
                    ok = ((unsigned)(v0 >> 32) == tgt) &                      \
                         ((unsigned)(v1 >> 32) == tgt);                       \
                    if (__all(ok)) break;                                     \
                    __builtin_amdgcn_s_sleep(1);                              \
                    if (++spins > 16384u) { dead = 1; break; }                \
                }                                                             \
            }                                                                 \
            /* 10. stage partner half of h_T into hlds[PAR^1] */              \
            _Pragma("unroll")                                                 \
            for (int r = 0; r < 4; ++r) {                                     \
                int row = kg * 4 + r;                                         \
                int byte = row * 512 + ((2 * pcol) ^ ((row & 7) << 4));       \
                unsigned v = (r < 2) ? (unsigned)v0 : (unsigned)v1;           \
                *(short*)((char*)hlds[(PAR) ^ 1] + byte) =                    \
                    (short)((r & 1) ? (v >> 16) : v);                         \
            }                                                                 \
        }                                                                     \
        /* 11. single barrier per step: all LDS writes visible */             \
        asm volatile("s_waitcnt lgkmcnt(0)" ::: "memory");                    \
        __builtin_amdgcn_s_barrier();                                         \
        asm volatile("" ::: "memory");                                        \
    } while (0)

#pragma unroll 1
    for (int tt = 0; tt < T_N; tt += 2) {
        STEP(0, tt);
        STEP(1, tt + 1);
    }

    // epilogue: final (hy[-1], cy[-1]) copies (h,c of last step already stored)
    {
        char* fh = out + 2 * HY_BYTES + (size_t)(g * 16 + kg * 4) * 1024 + (size_t)col * 4;
        char* fc = fh + 65536;
#pragma unroll
        for (int r = 0; r < 4; ++r) {
            *(float*)(fh + r * 1024) = hnew[r];
            *(float*)(fc + r * 1024) = cst[r];
        }
    }
#undef STEP
#undef XG_LOAD
}

// ---------------------------------------------------------------------------
// Fallback (WS_V1 <= ws < WS_V2): round-10 kernel (proven 5.95 ms).
// ---------------------------------------------------------------------------
__global__ __launch_bounds__(512)
__attribute__((amdgpu_waves_per_eu(2, 2)))
void lstm_rec8(
        const float* __restrict__ h0, const float* __restrict__ c0,
        const float* __restrict__ w_hh, char* __restrict__ out,
        char* __restrict__ ws)
{
    const int b    = blockIdx.x;
    const int g    = b & 3;
    const int hf   = b >> 2;
    const int tid  = threadIdx.x;
    const int w    = tid >> 6;
    const int lane = tid & 63;
    const int l15  = lane & 15;
    const int kg   = lane >> 4;

    const int tc   = hf * 8 + w;
    const int ptc  = (hf ^ 1) * 8 + w;
    const int col  = tc * 16 + l15;
    const int pcol = ptc * 16 + l15;

    __shared__ short hlds[2][4096];

    u64* exch = (u64*)ws;
    unsigned* flags = (unsigned*)(ws + EXCH_BYTES);
    const size_t myx = ((size_t)b * 8 + w) * 64 + lane;
    const size_t pbx = ((size_t)(b ^ 4) * 8 + w) * 64 + lane;
    unsigned* myflag = &flags[b * 8 + w];
    unsigned* pflag  = &flags[(b ^ 4) * 8 + w];

    s16x8 wreg[4][8];
#pragma unroll
    for (int q = 0; q < 4; ++q) {
        const int tau = 16 * q + tc;
        const float scale = (q == 2) ? -C2 : -C1;
        const float* wp = w_hh + (size_t)(tau * 16 + l15) * H_N;
#pragma unroll
        for (int ks = 0; ks < 8; ++ks) {
            const float* p = wp + ks * 32 + kg * 8;
            f32x4 w0 = *(const f32x4*)(p);
            f32x4 w1 = *(const f32x4*)(p + 4);
            s16x8 v;
            v[0]=f2bf(scale*w0[0]); v[1]=f2bf(scale*w0[1]);
            v[2]=f2bf(scale*w0[2]); v[3]=f2bf(scale*w0[3]);
            v[4]=f2bf(scale*w1[0]); v[5]=f2bf(scale*w1[1]);
            v[6]=f2bf(scale*w1[2]); v[7]=f2bf(scale*w1[3]);
            wreg[q][ks] = v;
        }
    }

    {
        const int row  = tid >> 5;
        const int col0 = (tid & 31) * 8;
        const float* hp = h0 + (size_t)(g * 16 + row) * H_N + col0;
        const int sw = (row & 7) << 4;
#pragma unroll
        for (int j = 0; j < 8; ++j) {
            int byte = row * 512 + ((2 * (col0 + j)) ^ sw);
            *(short*)((char*)hlds[0] + byte) = f2bf(hp[j]);
        }
    }

    float cst[4];
#pragma unroll
    for (int r = 0; r < 4; ++r)
        cst[r] = c0[(size_t)(g * 16 + kg * 4 + r) * H_N + col];

    float hnew[4] = {};
    unsigned dead = 0;

    __syncthreads();

    const char* p_xg0 = out + (size_t)g * 16384 + (size_t)tc * 512 + (size_t)lane * 8;
    const char* p_xg1 = p_xg0 + 16 * 512;
    const char* p_xg2 = out + HY_BYTES + (size_t)g * 16384 + (size_t)tc * 512 + (size_t)lane * 8;
    const char* p_xg3 = p_xg2 + 16 * 512;
    char* st_h = out + (size_t)(g * 16 + kg * 4) * 1024 + (size_t)col * 4;
    char* st_c = st_h + HY_BYTES;

    const int amask = (l15 & 7) << 4;

    s16x4 xg[4];

#define XG_LOAD(T) do {                                                       \
        const size_t _o = ((size_t)(T) << 16);                                \
        xg[0] = ntl4(p_xg0 + _o);  xg[1] = ntl4(p_xg1 + _o);                  \
        xg[2] = ntl4(p_xg2 + _o);  xg[3] = ntl4(p_xg3 + _o);                  \
    } while (0)

    XG_LOAD(0);
    asm volatile("s_waitcnt vmcnt(0)" ::: "memory");

#define STEP(PAR, T) do {                                                     \
        if ((T) > 0) {                                                        \
            char* _hp = st_h + ((size_t)((T) - 1) << 16);                     \
            char* _cp = st_c + ((size_t)((T) - 1) << 16);                     \
            _Pragma("unroll")                                                 \
            for (int r = 0; r < 4; ++r) {                                     \
                *(float*)(_hp + r * 1024) = hnew[r];                          \
                *(float*)(_cp + r * 1024) = cst[r];                           \
            }                                                                 \
        }                                                                     \
        unsigned fv = __hip_atomic_load(pflag, __ATOMIC_RELAXED,              \
                                        __HIP_MEMORY_SCOPE_AGENT);            \
        f32x4 acc[4];                                                         \
        _Pragma("unroll")                                                     \
        for (int q = 0; q < 4; ++q) {                                         \
            acc[q][0] = bf2f(xg[q][0]); acc[q][1] = bf2f(xg[q][1]);           \
            acc[q][2] = bf2f(xg[q][2]); acc[q][3] = bf2f(xg[q][3]);           \
        }                                                                     \
        _Pragma("unroll")                                                     \
        for (int ks = 0; ks < 8; ++ks) {                                      \
            s16x8 av = *(const s16x8*)((const char*)hlds[PAR] +               \
                            l15 * 512 + ((ks * 64 + kg * 16) ^ amask));       \
            acc[0] = MFMA(av, wreg[0][ks], acc[0]);                           \
            acc[1] = MFMA(av, wreg[1][ks], acc[1]);                           \
            acc[2] = MFMA(av, wreg[2][ks], acc[2]);                           \
            acc[3] = MFMA(av, wreg[3][ks], acc[3]);                           \
        }                                                                     \
        unsigned pk0, pk1;                                                    \
        {                                                                     \
            _Pragma("unroll")                                                 \
            for (int r = 0; r < 4; ++r) {                                     \
                float Ei = e2c(acc[0][r]);                                    \
                float Ef = e2c(acc[1][r]);                                    \
                float Eg = e2c(acc[2][r]);                                    \
                float Eo = e2c(acc[3][r]);                                    \
                float ai = 1.0f + Ei, af = 1.0f + Ef;                         \
                float ag = 1.0f + Eg, ao = 1.0f + Eo;                         \
                float r1 = __builtin_amdgcn_rcpf(ai * af);                    \
                float gi = r1 * af;                                           \
                float gf = r1 * ai;                                           \
                float r2 = __builtin_amdgcn_rcpf(ag * ao);                    \
                float go = r2 * ag;                                           \
                float tg = 2.0f * (r2 * ao) - 1.0f;                           \
                float c  = gf * cst[r] + gi * tg;                             \
                cst[r] = c;                                                   \
                float Ec = e2c(-C2 * c);                                      \
                float tc_ = 2.0f * __builtin_amdgcn_rcpf(1.0f + Ec) - 1.0f;   \
                hnew[r] = go * tc_;                                           \
            }                                                                 \
            unsigned s0 = (unsigned short)f2bf(hnew[0]);                      \
            unsigned s1 = (unsigned short)f2bf(hnew[1]);                      \
            unsigned s2 = (unsigned short)f2bf(hnew[2]);                      \
            unsigned s3 = (unsigned short)f2bf(hnew[3]);                      \
            pk0 = s0 | (s1 << 16);                                            \
            pk1 = s2 | (s3 << 16);                                            \
            _Pragma("unroll")                                                 \
            for (int r = 0; r < 4; ++r) {                                     \
                int row = kg * 4 + r;                                         \
                int byte = row * 512 + ((2 * col) ^ ((row & 7) << 4));        \
                unsigned v = (r < 2) ? pk0 : pk1;                             \
                *(short*)((char*)hlds[(PAR) ^ 1] + byte) =                    \
                    (short)((r & 1) ? (v >> 16) : v);                         \
            }                                                                 \
        }                                                                     \
        if ((T) + 1 < T_N) {                                                  \
            unsigned long long val = ((unsigned long long)pk1 << 32) | pk0;   \
            __hip_atomic_store(exch + (size_t)(PAR) * 4096 + myx, val,        \
                               __ATOMIC_RELAXED, __HIP_MEMORY_SCOPE_AGENT);   \
            asm volatile("s_waitcnt vmcnt(0)" ::: "memory");                  \
            if (lane == 0)                                                    \
                __hip_atomic_store(myflag, (unsigned)((T) + 1),               \
                                   __ATOMIC_RELAXED,                          \
                                   __HIP_MEMORY_SCOPE_AGENT);                 \
            XG_LOAD((T) + 1);                                                 \
            if (fv < (unsigned)((T) + 1) && !dead) {                          \
                unsigned spins = 0;                                           \
                while (__hip_atomic_load(pflag, __ATOMIC_RELAXED,             \
                                         __HIP_MEMORY_SCOPE_AGENT)           \
                       < (unsigned)((T) + 1)) {                               \
                    __builtin_amdgcn_s_sleep(1);                              \
                    if (++spins > 16384u) { dead = 1; break; }                \
                }                                                             \
            }                                                                 \
            unsigned long long pvv = __hip_atomic_load(                       \
                exch + (size_t)(PAR) * 4096 + pbx,                            \
                __ATOMIC_RELAXED, __HIP_MEMORY_SCOPE_AGENT);                  \
            _Pragma("unroll")                                                 \
            for (int r = 0; r < 4; ++r) {                                     \
                int row = kg * 4 + r;                                         \
                int byte = row * 512 + ((2 * pcol) ^ ((row & 7) << 4));       \
                *(short*)((char*)hlds[(PAR) ^ 1] + byte) =                    \
                    (short)(pvv >> (16 * r));                                 \
            }                                                                 \
        }                                                                     \
        asm volatile("s_waitcnt lgkmcnt(0)" ::: "memory");                    \
        __builtin_amdgcn_s_barrier();                                         \
        asm volatile("" ::: "memory");                                        \
    } while (0)

#pragma unroll 1
    for (int tt = 0; tt < T_N; tt += 2) {
        STEP(0, tt);
        STEP(1, tt + 1);
    }

    {
        char* hp = st_h + ((size_t)(T_N - 1) << 16);
        char* cp = st_c + ((size_t)(T_N - 1) << 16);
        char* fh = out + 2 * HY_BYTES + (size_t)(g * 16 + kg * 4) * 1024 + (size_t)col * 4;
        char* fc = fh + 65536;
#pragma unroll
        for (int r = 0; r < 4; ++r) {
            *(float*)(hp + r * 1024) = hnew[r];
            *(float*)(cp + r * 1024) = cst[r];
            *(float*)(fh + r * 1024) = hnew[r];
            *(float*)(fc + r * 1024) = cst[r];
        }
    }
#undef STEP
#undef XG_LOAD
}

extern "C" void kernel_launch(void* const* d_in, const int* in_sizes, int n_in,
                              void* d_out, int out_size, void* d_ws, size_t ws_size,
                              hipStream_t stream) {
    (void)in_sizes; (void)n_in; (void)out_size;
    const float* x    = (const float*)d_in[0];
    const float* h0   = (const float*)d_in[1];
    const float* c0   = (const float*)d_in[2];
    const float* w_ih = (const float*)d_in[3];
    const float* w_hh = (const float*)d_in[4];
    const float* b_ih = (const float*)d_in[5];
    const float* b_hh = (const float*)d_in[6];
    char* out = (char*)d_out;

    if (ws_size >= WS_V2) {
        // data-embedded counters: exact-match compare makes stale/poison
        // content harmless -> no flag-zeroing launch needed
        xg_gemm<<<dim3(1024, 4), 512, 0, stream>>>(x, w_ih, b_ih, b_hh, out);
        lstm_rec8v4<<<8, 512, 0, stream>>>(h0, c0, w_hh, out, (char*)d_ws);
    } else {
        zero_flags<<<1, 64, 0, stream>>>((char*)d_ws);
        xg_gemm<<<dim3(1024, 4), 512, 0, stream>>>(x, w_ih, b_ih, b_hh, out);
        lstm_rec8<<<8, 512, 0, stream>>>(h0, c0, w_hh, out, (char*)d_ws);
    }
}

// Round 15
// 4760.355 us; speedup vs baseline: 1.5035x; 1.0801x over previous
//
#include <hip/hip_runtime.h>

typedef short s16x8 __attribute__((ext_vector_type(8)));
typedef short s16x4 __attribute__((ext_vector_type(4)));
typedef float f32x4 __attribute__((ext_vector_type(4)));
typedef unsigned long long u64;

#define T_N 2048
#define B_N 64
#define H_N 256
#define I_N 256
#define HY_BYTES ((size_t)134217728)   // 4 * T * B * H
// v2: exch u64[2 parity][8 wg][8 wave][64 lane][2] = 128 KB, data|ctr fused
#define WS_V2 131072
// v1 (r10): exch 64KB + u32 flags[64]
#define EXCH_BYTES 65536
#define WS_V1 (EXCH_BYTES + 256)

static __device__ __forceinline__ short f2bf(float f) {
    unsigned u = __builtin_bit_cast(unsigned, f);
    u += 0x7FFFu + ((u >> 16) & 1u);   // RNE
    return (short)(u >> 16);
}
static __device__ __forceinline__ float bf2f(short h) {
    unsigned u = ((unsigned)(unsigned short)h) << 16;
    return __builtin_bit_cast(float, u);
}
static __device__ __forceinline__ float e2c(float a) {
    return __builtin_amdgcn_exp2f(fminf(a, 126.0f));
}
static __device__ __forceinline__ s16x4 ntl4(const void* p) {
    return __builtin_nontemporal_load((const s16x4*)p);
}

#define C1 1.44269504088896340f   // log2(e)
#define C2 2.88539008177792681f   // 2*log2(e)

#define MFMA(a, b, c) __builtin_amdgcn_mfma_f32_16x16x32_bf16(a, b, c, 0, 0, 0)

// ---------------------------------------------------------------------------
// zero flags (v1 fallback path only; ws not re-poisoned per replay)
// ---------------------------------------------------------------------------
__global__ void zero_flags(char* __restrict__ ws) {
    if (threadIdx.x < 64) ((unsigned*)(ws + EXCH_BYTES))[threadIdx.x] = 0u;
}

// ---------------------------------------------------------------------------
// Phase 1: xg = x @ w_ih^T + bias, pre-scaled by -C1 (i,f,o) / -C2 (g),
// bf16 in MFMA C-fragment layout inside d_out (unchanged).
// ---------------------------------------------------------------------------
__global__ __launch_bounds__(512) void xg_gemm(
        const float* __restrict__ x, const float* __restrict__ w_ih,
        const float* __restrict__ b_ih, const float* __restrict__ b_hh,
        char* __restrict__ out)
{
    const int tid  = threadIdx.x;
    const int wave = tid >> 6;
    const int lane = tid & 63;
    const int l15  = lane & 15;
    const int kg   = lane >> 4;

    __shared__ short Blds[8192];

    const int m16 = blockIdx.x * 8 + wave;
    const int by  = blockIdx.y;
    const int n0  = by * 256;

    const float* xrow = x + (size_t)(m16 * 16 + l15) * I_N;

    f32x4 acc[16] = {};

#pragma unroll 1
    for (int ks = 0; ks < 8; ++ks) {
        __syncthreads();
#pragma unroll
        for (int h = 0; h < 2; ++h) {
            int nl = (tid >> 2) + h * 128;
            int c  = tid & 3;
            const float* wp = w_ih + (size_t)(n0 + nl) * I_N + ks * 32 + c * 8;
            f32x4 w0 = *(const f32x4*)(wp);
            f32x4 w1 = *(const f32x4*)(wp + 4);
            s16x8 bv;
            bv[0]=f2bf(w0[0]); bv[1]=f2bf(w0[1]); bv[2]=f2bf(w0[2]); bv[3]=f2bf(w0[3]);
            bv[4]=f2bf(w1[0]); bv[5]=f2bf(w1[1]); bv[6]=f2bf(w1[2]); bv[7]=f2bf(w1[3]);
            int dt = nl >> 4;
            int lp = (nl & 15) + 16 * c;
            *(s16x8*)(&Blds[(dt * 64 + lp) * 8]) = bv;
        }
        __syncthreads();
        const float* ap = xrow + ks * 32 + kg * 8;
        f32x4 a0 = *(const f32x4*)(ap);
        f32x4 a1 = *(const f32x4*)(ap + 4);
        s16x8 av;
        av[0]=f2bf(a0[0]); av[1]=f2bf(a0[1]); av[2]=f2bf(a0[2]); av[3]=f2bf(a0[3]);
        av[4]=f2bf(a1[0]); av[5]=f2bf(a1[1]); av[6]=f2bf(a1[2]); av[7]=f2bf(a1[3]);
#pragma unroll
        for (int dt = 0; dt < 16; ++dt) {
            s16x8 bv = *(const s16x8*)(&Blds[(dt * 64 + lane) * 8]);
            acc[dt] = MFMA(av, bv, acc[dt]);
        }
    }

    const int t = m16 >> 2;
    const int g = m16 & 3;
#pragma unroll
    for (int dt = 0; dt < 16; ++dt) {
        int tau = by * 16 + dt;
        int n   = tau * 16 + l15;
        float bias = b_ih[n] + b_hh[n];
        float scale = ((tau >> 4) == 2) ? -C2 : -C1;
        size_t base = (tau < 32)
            ? ((size_t)t * 65536 + (size_t)g * 16384 + (size_t)tau * 512)
            : (HY_BYTES + (size_t)t * 65536 + (size_t)g * 16384 + (size_t)(tau - 32) * 512);
        s16x4 o;
        o[0] = f2bf(scale * (acc[dt][0] + bias));
        o[1] = f2bf(scale * (acc[dt][1] + bias));
        o[2] = f2bf(scale * (acc[dt][2] + bias));
        o[3] = f2bf(scale * (acc[dt][3] + bias));
        *(s16x4*)(out + base + lane * 8) = o;
    }
}

// ---------------------------------------------------------------------------
// Phase 2 v2 (proven 4.76 ms): r10 structure with DATA-EMBEDDED COUNTERS.
// Each lane publishes its 4 h values as two u64 words: low 32 = 2 bf16,
// high 32 = step counter.  Writer: two relaxed agent stores, NO drain, NO
// flag.  Reader: polls the data words until both counters == exact target
// (stale/poison never match), then uses the data from the same loads.
// The single combined vmcnt drain at the check overlaps publish-ack, xg HBM
// latency and pv L3 latency in ONE wait (~900 cyc) — r13/r14 proved that
// splitting these waits serializes them and regresses.
// Sticky bounded poll: broken sync -> fast absmax failure, never a hang.
// ---------------------------------------------------------------------------
__global__ __launch_bounds__(512)
__attribute__((amdgpu_waves_per_eu(2, 2)))
void lstm_rec8v2(
        const float* __restrict__ h0, const float* __restrict__ c0,
        const float* __restrict__ w_hh, char* __restrict__ out,
        char* __restrict__ ws)
{
    const int b    = blockIdx.x;       // 0..7
    const int g    = b & 3;
    const int hf   = b >> 2;
    const int tid  = threadIdx.x;
    const int w    = tid >> 6;
    const int lane = tid & 63;
    const int l15  = lane & 15;
    const int kg   = lane >> 4;

    const int tc   = hf * 8 + w;       // my col-tile (0..15)
    const int ptc  = (hf ^ 1) * 8 + w; // partner col-tile staged by this wave
    const int col  = tc * 16 + l15;
    const int pcol = ptc * 16 + l15;

    __shared__ short hlds[2][4096];    // double-buffered 16x256 bf16, swizzled

    u64* exch = (u64*)ws;
    // [parity][wg][wave][lane][2]: parity stride 8192 u64
    const size_t myx = (size_t)b * 1024 + (size_t)w * 128 + (size_t)lane * 2;
    const size_t pbx = (size_t)(b ^ 4) * 1024 + (size_t)w * 128 + (size_t)lane * 2;

    // ---- W fragments: 4 gate tiles, pre-scaled, register-resident ----
    s16x8 wreg[4][8];
#pragma unroll
    for (int q = 0; q < 4; ++q) {
        const int tau = 16 * q + tc;
        const float scale = (q == 2) ? -C2 : -C1;
        const float* wp = w_hh + (size_t)(tau * 16 + l15) * H_N;
#pragma unroll
        for (int ks = 0; ks < 8; ++ks) {
            const float* p = wp + ks * 32 + kg * 8;
            f32x4 w0 = *(const f32x4*)(p);
            f32x4 w1 = *(const f32x4*)(p + 4);
            s16x8 v;
            v[0]=f2bf(scale*w0[0]); v[1]=f2bf(scale*w0[1]);
            v[2]=f2bf(scale*w0[2]); v[3]=f2bf(scale*w0[3]);
            v[4]=f2bf(scale*w1[0]); v[5]=f2bf(scale*w1[1]);
            v[6]=f2bf(scale*w1[2]); v[7]=f2bf(scale*w1[3]);
            wreg[q][ks] = v;
        }
    }

    // ---- h0 -> hlds[0] (full 256 cols, bf16, XOR swizzle per row) ----
    {
        const int row  = tid >> 5;
        const int col0 = (tid & 31) * 8;
        const float* hp = h0 + (size_t)(g * 16 + row) * H_N + col0;
        const int sw = (row & 7) << 4;
#pragma unroll
        for (int j = 0; j < 8; ++j) {
            int byte = row * 512 + ((2 * (col0 + j)) ^ sw);
            *(short*)((char*)hlds[0] + byte) = f2bf(hp[j]);
        }
    }

    // ---- c0 -> registers (my cols only) ----
    float cst[4];
#pragma unroll
    for (int r = 0; r < 4; ++r)
        cst[r] = c0[(size_t)(g * 16 + kg * 4 + r) * H_N + col];

    float hnew[4] = {};
    unsigned dead = 0;    // sticky poll-timeout marker

    __syncthreads();

    const char* p_xg0 = out + (size_t)g * 16384 + (size_t)tc * 512 + (size_t)lane * 8;           // i
    const char* p_xg1 = p_xg0 + 16 * 512;                                                         // f
    const char* p_xg2 = out + HY_BYTES + (size_t)g * 16384 + (size_t)tc * 512 + (size_t)lane * 8; // g
    const char* p_xg3 = p_xg2 + 16 * 512;                                                         // o
    char* st_h = out + (size_t)(g * 16 + kg * 4) * 1024 + (size_t)col * 4;
    char* st_c = st_h + HY_BYTES;

    const int amask = (l15 & 7) << 4;

    s16x4 xg[4];

#define XG_LOAD(T) do {                                                       \
        const size_t _o = ((size_t)(T) << 16);                                \
        xg[0] = ntl4(p_xg0 + _o);  xg[1] = ntl4(p_xg1 + _o);                  \
        xg[2] = ntl4(p_xg2 + _o);  xg[3] = ntl4(p_xg3 + _o);                  \
    } while (0)

    XG_LOAD(0);
    asm volatile("s_waitcnt vmcnt(0)" ::: "memory");

#define STEP(PAR, T) do {                                                     \
        /* h,c outputs of step T-1 (cached stores; never waited on) */        \
        if ((T) > 0) {                                                        \
            char* _hp = st_h + ((size_t)((T) - 1) << 16);                     \
            char* _cp = st_c + ((size_t)((T) - 1) << 16);                     \
            _Pragma("unroll")                                                 \
            for (int r = 0; r < 4; ++r) {                                     \
                *(float*)(_hp + r * 1024) = hnew[r];                          \
                *(float*)(_cp + r * 1024) = cst[r];                           \
            }                                                                 \
        }                                                                     \
        /* acc <- pre-scaled xg fragment (identical layout) */                \
        f32x4 acc[4];                                                         \
        _Pragma("unroll")                                                     \
        for (int q = 0; q < 4; ++q) {                                         \
            acc[q][0] = bf2f(xg[q][0]); acc[q][1] = bf2f(xg[q][1]);           \
            acc[q][2] = bf2f(xg[q][2]); acc[q][3] = bf2f(xg[q][3]);           \
        }                                                                     \
        /* gates += h_T @ (scaled W)^T  (full k=256; W in regs) */            \
        _Pragma("unroll")                                                     \
        for (int ks = 0; ks < 8; ++ks) {                                      \
            s16x8 av = *(const s16x8*)((const char*)hlds[PAR] +               \
                            l15 * 512 + ((ks * 64 + kg * 16) ^ amask));       \
            acc[0] = MFMA(av, wreg[0][ks], acc[0]);                           \
            acc[1] = MFMA(av, wreg[1][ks], acc[1]);                           \
            acc[2] = MFMA(av, wreg[2][ks], acc[2]);                           \
            acc[3] = MFMA(av, wreg[3][ks], acc[3]);                           \
        }                                                                     \
        /* activations (exp2 fed directly by pre-scaled gates) */             \
        unsigned pk0, pk1;                                                    \
        {                                                                     \
            _Pragma("unroll")                                                 \
            for (int r = 0; r < 4; ++r) {                                     \
                float Ei = e2c(acc[0][r]);                                    \
                float Ef = e2c(acc[1][r]);                                    \
                float Eg = e2c(acc[2][r]);                                    \
                float Eo = e2c(acc[3][r]);                                    \
                float ai = 1.0f + Ei, af = 1.0f + Ef;                         \
                float ag = 1.0f + Eg, ao = 1.0f + Eo;                         \
                float r1 = __builtin_amdgcn_rcpf(ai * af);                    \
                float gi = r1 * af;                                           \
                float gf = r1 * ai;                                           \
                float r2 = __builtin_amdgcn_rcpf(ag * ao);                    \
                float go = r2 * ag;                                           \
                float tg = 2.0f * (r2 * ao) - 1.0f;                           \
                float c  = gf * cst[r] + gi * tg;                             \
                cst[r] = c;                                                   \
                float Ec = e2c(-C2 * c);                                      \
                float tc_ = 2.0f * __builtin_amdgcn_rcpf(1.0f + Ec) - 1.0f;   \
                hnew[r] = go * tc_;                                           \
            }                                                                 \
            unsigned s0 = (unsigned short)f2bf(hnew[0]);                      \
            unsigned s1 = (unsigned short)f2bf(hnew[1]);                      \
            unsigned s2 = (unsigned short)f2bf(hnew[2]);                      \
            unsigned s3 = (unsigned short)f2bf(hnew[3]);                      \
            pk0 = s0 | (s1 << 16);                                            \
            pk1 = s2 | (s3 << 16);                                            \
        }                                                                     \
        if ((T) + 1 < T_N) {                                                  \
            /* publish data|ctr fused — fire and forget, NO drain, NO flag */ \
            u64 c64 = ((u64)(unsigned)((T) + 1)) << 32;                       \
            u64* _m = exch + (size_t)(PAR) * 8192 + myx;                      \
            __hip_atomic_store(_m,     (u64)pk0 | c64,                        \
                               __ATOMIC_RELAXED, __HIP_MEMORY_SCOPE_AGENT);   \
            __hip_atomic_store(_m + 1, (u64)pk1 | c64,                        \
                               __ATOMIC_RELAXED, __HIP_MEMORY_SCOPE_AGENT);   \
        }                                                                     \
        /* own-half h -> hlds[PAR^1] */                                       \
        _Pragma("unroll")                                                     \
        for (int r = 0; r < 4; ++r) {                                         \
            int row = kg * 4 + r;                                             \
            int byte = row * 512 + ((2 * col) ^ ((row & 7) << 4));            \
            unsigned v = (r < 2) ? pk0 : pk1;                                 \
            *(short*)((char*)hlds[(PAR) ^ 1] + byte) =                        \
                (short)((r & 1) ? (v >> 16) : v);                             \
        }                                                                     \
        if ((T) + 1 < T_N) {                                                  \
            XG_LOAD((T) + 1);                                                 \
            /* poll partner data directly: both ctrs must equal T+1 */        \
            u64 v0 = 0, v1 = 0;                                               \
            if (!dead) {                                                      \
                const u64* _p = exch + (size_t)(PAR) * 8192 + pbx;            \
                const unsigned tgt = (unsigned)((T) + 1);                     \
                unsigned spins = 0;                                           \
                for (;;) {                                                    \
                    v0 = __hip_atomic_load(_p,     __ATOMIC_RELAXED,          \
                                           __HIP_MEMORY_SCOPE_AGENT);         \
                    v1 = __hip_atomic_load(_p + 1, __ATOMIC_RELAXED,          \
                                           __HIP_MEMORY_SCOPE_AGENT);         \
                    int ok = ((unsigned)(v0 >> 32) == tgt) &                  \
                             ((unsigned)(v1 >> 32) == tgt);                   \
                    if (__all(ok)) break;                                     \
                    __builtin_amdgcn_s_sleep(1);                              \
                    if (++spins > 16384u) { dead = 1; break; }                \
                }                                                             \
            }                                                                 \
            /* stage partner half of h_T into hlds[PAR^1] */                  \
            _Pragma("unroll")                                                 \
            for (int r = 0; r < 4; ++r) {                                     \
                int row = kg * 4 + r;                                         \
                int byte = row * 512 + ((2 * pcol) ^ ((row & 7) << 4));       \
                unsigned v = (r < 2) ? (unsigned)v0 : (unsigned)v1;           \
                *(short*)((char*)hlds[(PAR) ^ 1] + byte) =                    \
                    (short)((r & 1) ? (v >> 16) : v);                         \
            }                                                                 \
        }                                                                     \
        /* single barrier per step: all LDS writes visible */                 \
        asm volatile("s_waitcnt lgkmcnt(0)" ::: "memory");                    \
        __builtin_amdgcn_s_barrier();                                         \
        asm volatile("" ::: "memory");                                        \
    } while (0)

#pragma unroll 1
    for (int tt = 0; tt < T_N; tt += 2) {
        STEP(0, tt);
        STEP(1, tt + 1);
    }

    // epilogue: h,c of last step + final (hy[-1], cy[-1]) for my cols
    {
        char* hp = st_h + ((size_t)(T_N - 1) << 16);
        char* cp = st_c + ((size_t)(T_N - 1) << 16);
        char* fh = out + 2 * HY_BYTES + (size_t)(g * 16 + kg * 4) * 1024 + (size_t)col * 4;
        char* fc = fh + 65536;
#pragma unroll
        for (int r = 0; r < 4; ++r) {
            *(float*)(hp + r * 1024) = hnew[r];
            *(float*)(cp + r * 1024) = cst[r];
            *(float*)(fh + r * 1024) = hnew[r];
            *(float*)(fc + r * 1024) = cst[r];
        }
    }
#undef STEP
#undef XG_LOAD
}

// ---------------------------------------------------------------------------
// Fallback (WS_V1 <= ws < WS_V2): round-10 kernel (proven 5.95 ms).
// ---------------------------------------------------------------------------
__global__ __launch_bounds__(512)
__attribute__((amdgpu_waves_per_eu(2, 2)))
void lstm_rec8(
        const float* __restrict__ h0, const float* __restrict__ c0,
        const float* __restrict__ w_hh, char* __restrict__ out,
        char* __restrict__ ws)
{
    const int b    = blockIdx.x;
    const int g    = b & 3;
    const int hf   = b >> 2;
    const int tid  = threadIdx.x;
    const int w    = tid >> 6;
    const int lane = tid & 63;
    const int l15  = lane & 15;
    const int kg   = lane >> 4;

    const int tc   = hf * 8 + w;
    const int ptc  = (hf ^ 1) * 8 + w;
    const int col  = tc * 16 + l15;
    const int pcol = ptc * 16 + l15;

    __shared__ short hlds[2][4096];

    u64* exch = (u64*)ws;
    unsigned* flags = (unsigned*)(ws + EXCH_BYTES);
    const size_t myx = ((size_t)b * 8 + w) * 64 + lane;
    const size_t pbx = ((size_t)(b ^ 4) * 8 + w) * 64 + lane;
    unsigned* myflag = &flags[b * 8 + w];
    unsigned* pflag  = &flags[(b ^ 4) * 8 + w];

    s16x8 wreg[4][8];
#pragma unroll
    for (int q = 0; q < 4; ++q) {
        const int tau = 16 * q + tc;
        const float scale = (q == 2) ? -C2 : -C1;
        const float* wp = w_hh + (size_t)(tau * 16 + l15) * H_N;
#pragma unroll
        for (int ks = 0; ks < 8; ++ks) {
            const float* p = wp + ks * 32 + kg * 8;
            f32x4 w0 = *(const f32x4*)(p);
            f32x4 w1 = *(const f32x4*)(p + 4);
            s16x8 v;
            v[0]=f2bf(scale*w0[0]); v[1]=f2bf(scale*w0[1]);
            v[2]=f2bf(scale*w0[2]); v[3]=f2bf(scale*w0[3]);
            v[4]=f2bf(scale*w1[0]); v[5]=f2bf(scale*w1[1]);
            v[6]=f2bf(scale*w1[2]); v[7]=f2bf(scale*w1[3]);
            wreg[q][ks] = v;
        }
    }

    {
        const int row  = tid >> 5;
        const int col0 = (tid & 31) * 8;
        const float* hp = h0 + (size_t)(g * 16 + row) * H_N + col0;
        const int sw = (row & 7) << 4;
#pragma unroll
        for (int j = 0; j < 8; ++j) {
            int byte = row * 512 + ((2 * (col0 + j)) ^ sw);
            *(short*)((char*)hlds[0] + byte) = f2bf(hp[j]);
        }
    }

    float cst[4];
#pragma unroll
    for (int r = 0; r < 4; ++r)
        cst[r] = c0[(size_t)(g * 16 + kg * 4 + r) * H_N + col];

    float hnew[4] = {};
    unsigned dead = 0;

    __syncthreads();

    const char* p_xg0 = out + (size_t)g * 16384 + (size_t)tc * 512 + (size_t)lane * 8;
    const char* p_xg1 = p_xg0 + 16 * 512;
    const char* p_xg2 = out + HY_BYTES + (size_t)g * 16384 + (size_t)tc * 512 + (size_t)lane * 8;
    const char* p_xg3 = p_xg2 + 16 * 512;
    char* st_h = out + (size_t)(g * 16 + kg * 4) * 1024 + (size_t)col * 4;
    char* st_c = st_h + HY_BYTES;

    const int amask = (l15 & 7) << 4;

    s16x4 xg[4];

#define XG_LOAD(T) do {                                                       \
        const size_t _o = ((size_t)(T) << 16);                                \
        xg[0] = ntl4(p_xg0 + _o);  xg[1] = ntl4(p_xg1 + _o);                  \
        xg[2] = ntl4(p_xg2 + _o);  xg[3] = ntl4(p_xg3 + _o);                  \
    } while (0)

    XG_LOAD(0);
    asm volatile("s_waitcnt vmcnt(0)" ::: "memory");

#define STEP(PAR, T) do {                                                     \
        if ((T) > 0) {                                                        \
            char* _hp = st_h + ((size_t)((T) - 1) << 16);                     \
            char* _cp = st_c + ((size_t)((T) - 1) << 16);                     \
            _Pragma("unroll")                                                 \
            for (int r = 0; r < 4; ++r) {                                     \
                *(float*)(_hp + r * 1024) = hnew[r];                          \
                *(float*)(_cp + r * 1024) = cst[r];                           \
            }                                                                 \
        }                                                                     \
        unsigned fv = __hip_atomic_load(pflag, __ATOMIC_RELAXED,              \
                                        __HIP_MEMORY_SCOPE_AGENT);            \
        f32x4 acc[4];                                                         \
        _Pragma("unroll")                                                     \
        for (int q = 0; q < 4; ++q) {                                         \
            acc[q][0] = bf2f(xg[q][0]); acc[q][1] = bf2f(xg[q][1]);           \
            acc[q][2] = bf2f(xg[q][2]); acc[q][3] = bf2f(xg[q][3]);           \
        }                                                                     \
        _Pragma("unroll")                                                     \
        for (int ks = 0; ks < 8; ++ks) {                                      \
            s16x8 av = *(const s16x8*)((const char*)hlds[PAR] +               \
                            l15 * 512 + ((ks * 64 + kg * 16) ^ amask));       \
            acc[0] = MFMA(av, wreg[0][ks], acc[0]);                           \
            acc[1] = MFMA(av, wreg[1][ks], acc[1]);                           \
            acc[2] = MFMA(av, wreg[2][ks], acc[2]);                           \
            acc[3] = MFMA(av, wreg[3][ks], acc[3]);                           \
        }                                                                     \
        unsigned pk0, pk1;                                                    \
        {                                                                     \
            _Pragma("unroll")                                                 \
            for (int r = 0; r < 4; ++r) {                                     \
                float Ei = e2c(acc[0][r]);                                    \
                float Ef = e2c(acc[1][r]);                                    \
                float Eg = e2c(acc[2][r]);                                    \
                float Eo = e2c(acc[3][r]);                                    \
                float ai = 1.0f + Ei, af = 1.0f + Ef;                         \
                float ag = 1.0f + Eg, ao = 1.0f + Eo;                         \
                float r1 = __builtin_amdgcn_rcpf(ai * af);                    \
                float gi = r1 * af;                                           \
                float gf = r1 * ai;                                           \
                float r2 = __builtin_amdgcn_rcpf(ag * ao);                    \
                float go = r2 * ag;                                           \
                float tg = 2.0f * (r2 * ao) - 1.0f;                           \
                float c  = gf * cst[r] + gi * tg;                             \
                cst[r] = c;                                                   \
                float Ec = e2c(-C2 * c);                                      \
                float tc_ = 2.0f * __builtin_amdgcn_rcpf(1.0f + Ec) - 1.0f;   \
                hnew[r] = go * tc_;                                           \
            }                                                                 \
            unsigned s0 = (unsigned short)f2bf(hnew[0]);                      \
            unsigned s1 = (unsigned short)f2bf(hnew[1]);                      \
            unsigned s2 = (unsigned short)f2bf(hnew[2]);                      \
            unsigned s3 = (unsigned short)f2bf(hnew[3]);                      \
            pk0 = s0 | (s1 << 16);                                            \
            pk1 = s2 | (s3 << 16);                                            \
            _Pragma("unroll")                                                 \
            for (int r = 0; r < 4; ++r) {                                     \
                int row = kg * 4 + r;                                         \
                int byte = row * 512 + ((2 * col) ^ ((row & 7) << 4));        \
                unsigned v = (r < 2) ? pk0 : pk1;                             \
                *(short*)((char*)hlds[(PAR) ^ 1] + byte) =                    \
                    (short)((r & 1) ? (v >> 16) : v);                         \
            }                                                                 \
        }                                                                     \
        if ((T) + 1 < T_N) {                                                  \
            unsigned long long val = ((unsigned long long)pk1 << 32) | pk0;   \
            __hip_atomic_store(exch + (size_t)(PAR) * 4096 + myx, val,        \
                               __ATOMIC_RELAXED, __HIP_MEMORY_SCOPE_AGENT);   \
            asm volatile("s_waitcnt vmcnt(0)" ::: "memory");                  \
            if (lane == 0)                                                    \
                __hip_atomic_store(myflag, (unsigned)((T) + 1),               \
                                   __ATOMIC_RELAXED,                          \
                                   __HIP_MEMORY_SCOPE_AGENT);                 \
            XG_LOAD((T) + 1);                                                 \
            if (fv < (unsigned)((T) + 1) && !dead) {                          \
                unsigned spins = 0;                                           \
                while (__hip_atomic_load(pflag, __ATOMIC_RELAXED,             \
                                         __HIP_MEMORY_SCOPE_AGENT)           \
                       < (unsigned)((T) + 1)) {                               \
                    __builtin_amdgcn_s_sleep(1);                              \
                    if (++spins > 16384u) { dead = 1; break; }                \
                }                                                             \
            }                                                                 \
            unsigned long long pvv = __hip_atomic_load(                       \
                exch + (size_t)(PAR) * 4096 + pbx,                            \
                __ATOMIC_RELAXED, __HIP_MEMORY_SCOPE_AGENT);                  \
            _Pragma("unroll")                                                 \
            for (int r = 0; r < 4; ++r) {                                     \
                int row = kg * 4 + r;                                         \
                int byte = row * 512 + ((2 * pcol) ^ ((row & 7) << 4));       \
                *(short*)((char*)hlds[(PAR) ^ 1] + byte) =                    \
                    (short)(pvv >> (16 * r));                                 \
            }                                                                 \
        }                                                                     \
        asm volatile("s_waitcnt lgkmcnt(0)" ::: "memory");                    \
        __builtin_amdgcn_s_barrier();                                         \
        asm volatile("" ::: "memory");                                        \
    } while (0)

#pragma unroll 1
    for (int tt = 0; tt < T_N; tt += 2) {
        STEP(0, tt);
        STEP(1, tt + 1);
    }

    {
        char* hp = st_h + ((size_t)(T_N - 1) << 16);
        char* cp = st_c + ((size_t)(T_N - 1) << 16);
        char* fh = out + 2 * HY_BYTES + (size_t)(g * 16 + kg * 4) * 1024 + (size_t)col * 4;
        char* fc = fh + 65536;
#pragma unroll
        for (int r = 0; r < 4; ++r) {
            *(float*)(hp + r * 1024) = hnew[r];
            *(float*)(cp + r * 1024) = cst[r];
            *(float*)(fh + r * 1024) = hnew[r];
            *(float*)(fc + r * 1024) = cst[r];
        }
    }
#undef STEP
#undef XG_LOAD
}

extern "C" void kernel_launch(void* const* d_in, const int* in_sizes, int n_in,
                              void* d_out, int out_size, void* d_ws, size_t ws_size,
                              hipStream_t stream) {
    (void)in_sizes; (void)n_in; (void)out_size;
    const float* x    = (const float*)d_in[0];
    const float* h0   = (const float*)d_in[1];
    const float* c0   = (const float*)d_in[2];
    const float* w_ih = (const float*)d_in[3];
    const float* w_hh = (const float*)d_in[4];
    const float* b_ih = (const float*)d_in[5];
    const float* b_hh = (const float*)d_in[6];
    char* out = (char*)d_out;

    if (ws_size >= WS_V2) {
        // data-embedded counters: exact-match compare makes stale/poison
        // content harmless -> no flag-zeroing launch needed
        xg_gemm<<<dim3(1024, 4), 512, 0, stream>>>(x, w_ih, b_ih, b_hh, out);
        lstm_rec8v2<<<8, 512, 0, stream>>>(h0, c0, w_hh, out, (char*)d_ws);
    } else {
        zero_flags<<<1, 64, 0, stream>>>((char*)d_ws);
        xg_gemm<<<dim3(1024, 4), 512, 0, stream>>>(x, w_ih, b_ih, b_hh, out);
        lstm_rec8<<<8, 512, 0, stream>>>(h0, c0, w_hh, out, (char*)d_ws);
    }
}